// Round 4
// baseline (1418.637 us; speedup 1.0000x reference)
//
#include <hip/hip_runtime.h>
#include <math.h>

#define HID      2048
#define STATE    128
#define HEADS    64
#define HEADDIM  64
#define INTER    4096
#define CONV_DIM 4352
#define PROJ     8512
#define NBATCH   2
#define SEQ      2048
#define BS       (NBATCH*SEQ)   /* 4096 token rows */
#define EPS      1e-5f
#define YN_COL   4160           /* YN lives in PRJ cols [4160, 8256) after conv/dt are dead */

typedef __attribute__((ext_vector_type(8))) short short8;
typedef __attribute__((ext_vector_type(4))) float f32x4;

__device__ inline unsigned short f2bf(float f) {
  union { float f; unsigned int u; } v; v.f = f;
  unsigned int r = v.u + 0x7fffu + ((v.u >> 16) & 1u);   // RNE
  return (unsigned short)(r >> 16);
}
__device__ inline float bf2f(unsigned short b) {
  union { unsigned int u; float f; } v; v.u = ((unsigned int)b) << 16;
  return v.f;
}

// ---------------- f32 -> bf16 cast (weights) ----------------
__global__ __launch_bounds__(256)
void cast_bf16_kernel(const float4* __restrict__ src, ushort4* __restrict__ dst, int n4) {
  int i = blockIdx.x * 256 + threadIdx.x;
  if (i >= n4) return;
  float4 v = src[i];
  ushort4 o;
  o.x = f2bf(v.x); o.y = f2bf(v.y); o.z = f2bf(v.z); o.w = f2bf(v.w);
  dst[i] = o;
}

// ---------------- input RMSNorm -> bf16 ----------------
__global__ __launch_bounds__(256)
void rmsnorm_in_kernel(const float* __restrict__ x, const float* __restrict__ w,
                       unsigned short* __restrict__ xn) {
  int row = blockIdx.x;
  int t = threadIdx.x;
  const float* xr = x + (size_t)row * HID;
  float4 a = ((const float4*)xr)[t];
  float4 b = ((const float4*)xr)[t + 256];
  float ss = a.x*a.x + a.y*a.y + a.z*a.z + a.w*a.w
           + b.x*b.x + b.y*b.y + b.z*b.z + b.w*b.w;
  for (int o = 32; o > 0; o >>= 1) ss += __shfl_down(ss, o);
  __shared__ float red[4];
  __shared__ float scl;
  if ((t & 63) == 0) red[t >> 6] = ss;
  __syncthreads();
  if (t == 0) scl = rsqrtf((red[0]+red[1]+red[2]+red[3]) / (float)HID + EPS);
  __syncthreads();
  float s = scl;
  float4 w0 = ((const float4*)w)[t];
  float4 w1 = ((const float4*)w)[t + 256];
  ushort4 o0, o1;
  o0.x = f2bf(a.x*s*w0.x); o0.y = f2bf(a.y*s*w0.y); o0.z = f2bf(a.z*s*w0.z); o0.w = f2bf(a.w*s*w0.w);
  o1.x = f2bf(b.x*s*w1.x); o1.y = f2bf(b.y*s*w1.y); o1.z = f2bf(b.z*s*w1.z); o1.w = f2bf(b.w*s*w1.w);
  ushort4* dst = (ushort4*)(xn + (size_t)row * HID);
  dst[t] = o0;
  dst[t + 256] = o1;
}

// ---------------- bf16 BT-GEMM: C[M,N] = A[M,K] * B[N,K]^T ----------------
// 128x128 block tile, 4 waves of 64x64, BK=32, mfma_f32_16x16x32_bf16,
// global_load_lds width=16 with XOR-chunk swizzle applied on the global side.
// A has row stride lda (elements); B has row stride Kd.
// Output: bf16 (Cb, row stride ldc) or f32 + residual (Cf, row stride N).
__global__ __launch_bounds__(256)
void gemm_bt_kernel(const unsigned short* __restrict__ A, int lda,
                    const unsigned short* __restrict__ B,
                    float* __restrict__ Cf, unsigned short* __restrict__ Cb, int ldc,
                    int M, int N, int Kd, const float* __restrict__ residual) {
  __shared__ unsigned short As[128 * 32];
  __shared__ unsigned short Bs[128 * 32];
  const int tid  = threadIdx.x;
  const int wave = tid >> 6;
  const int lane = tid & 63;
  const int quad = lane >> 4;
  const int tq   = lane & 15;
  const int m0 = blockIdx.x * 128;
  const int n0 = blockIdx.y * 128;
  const int wm = (wave >> 1) * 64;
  const int wn = (wave & 1) * 64;

  f32x4 acc[4][4];
#pragma unroll
  for (int i = 0; i < 4; i++)
#pragma unroll
    for (int jj = 0; jj < 4; jj++)
      acc[i][jj] = (f32x4){0.f, 0.f, 0.f, 0.f};

  // staging: linear 16B slot ci in [0,512); slot (r = ci>>2, cs = ci&3) holds
  // global chunk cg = cs ^ (r&3)  (XOR involutive -> read side uses same xor)
  const int ci0 = wave * 128 + lane;
  const int ci1 = ci0 + 64;
  const int rA0 = ci0 >> 2, cA0 = (ci0 & 3) ^ (rA0 & 3);
  const int rA1 = ci1 >> 2, cA1 = (ci1 & 3) ^ (rA1 & 3);
  const unsigned short* gA0 = A + (size_t)(m0 + rA0) * lda + cA0 * 8;
  const unsigned short* gA1 = A + (size_t)(m0 + rA1) * lda + cA1 * 8;
  int nb0 = n0 + rA0; nb0 = (nb0 > N - 1) ? (N - 1) : nb0;   // clamp OOB W rows (GEMM1 N=8512)
  int nb1 = n0 + rA1; nb1 = (nb1 > N - 1) ? (N - 1) : nb1;
  const unsigned short* gB0 = B + (size_t)nb0 * Kd + cA0 * 8;
  const unsigned short* gB1 = B + (size_t)nb1 * Kd + cA1 * 8;
  unsigned short* lA0 = As + wave * 1024;        // wave-uniform LDS base; HW adds lane*16B
  unsigned short* lA1 = As + wave * 1024 + 512;
  unsigned short* lB0 = Bs + wave * 1024;
  unsigned short* lB1 = Bs + wave * 1024 + 512;

  const int kIters = Kd >> 5;
  for (int kt = 0; kt < kIters; ++kt) {
    const int ko = kt << 5;
    __syncthreads();
    __builtin_amdgcn_global_load_lds((const __attribute__((address_space(1))) void*)(gA0 + ko),
                                     (__attribute__((address_space(3))) void*)lA0, 16, 0, 0);
    __builtin_amdgcn_global_load_lds((const __attribute__((address_space(1))) void*)(gA1 + ko),
                                     (__attribute__((address_space(3))) void*)lA1, 16, 0, 0);
    __builtin_amdgcn_global_load_lds((const __attribute__((address_space(1))) void*)(gB0 + ko),
                                     (__attribute__((address_space(3))) void*)lB0, 16, 0, 0);
    __builtin_amdgcn_global_load_lds((const __attribute__((address_space(1))) void*)(gB1 + ko),
                                     (__attribute__((address_space(3))) void*)lB1, 16, 0, 0);
    __syncthreads();   // drains vmcnt(0) before barrier -> LDS tiles complete

    short8 af[4], bf[4];
#pragma unroll
    for (int mi = 0; mi < 4; mi++) {
      int r = wm + mi * 16 + tq;
      af[mi] = *(const short8*)(As + r * 32 + ((quad ^ (r & 3)) << 3));
    }
#pragma unroll
    for (int ni = 0; ni < 4; ni++) {
      int r = wn + ni * 16 + tq;
      bf[ni] = *(const short8*)(Bs + r * 32 + ((quad ^ (r & 3)) << 3));
    }
#pragma unroll
    for (int mi = 0; mi < 4; mi++)
#pragma unroll
      for (int ni = 0; ni < 4; ni++)
        acc[mi][ni] = __builtin_amdgcn_mfma_f32_16x16x32_bf16(af[mi], bf[ni], acc[mi][ni], 0, 0, 0);
  }

  // epilogue: D row = quad*4 + reg, col = lane&15  [m89 verified mapping]
#pragma unroll
  for (int mi = 0; mi < 4; mi++) {
#pragma unroll
    for (int ni = 0; ni < 4; ni++) {
      int col = n0 + wn + ni * 16 + tq;
      if (col < N) {
        int rowb = m0 + wm + mi * 16 + quad * 4;
        if (Cb) {
#pragma unroll
          for (int r = 0; r < 4; r++)
            Cb[(size_t)(rowb + r) * ldc + col] = f2bf(acc[mi][ni][r]);
        } else {
#pragma unroll
          for (int r = 0; r < 4; r++) {
            size_t idx = (size_t)(rowb + r) * N + col;
            float v = acc[mi][ni][r];
            if (residual) v += residual[idx];
            Cf[idx] = v;
          }
        }
      }
    }
  }
}

// ---------------- causal depthwise conv(K=4) + bias + SiLU (bf16 in/out) ----------------
__global__ __launch_bounds__(256)
void conv_silu_kernel(const unsigned short* __restrict__ proj, const float* __restrict__ cw,
                      const float* __restrict__ cb, unsigned short* __restrict__ convo) {
  int idx = blockIdx.x * 256 + threadIdx.x;
  if (idx >= BS * CONV_DIM) return;
  int c  = idx % CONV_DIM;
  int rs = idx / CONV_DIM;
  int s  = rs & (SEQ - 1);
  const unsigned short* col = proj + (size_t)rs * PROJ + INTER + c;
  float acc = cb[c];
#pragma unroll
  for (int k = 0; k < 4; k++) {
    int sp = s - 3 + k;
    if (sp >= 0) acc += bf2f(col[(ptrdiff_t)(k - 3) * PROJ]) * cw[c * 4 + k];
  }
  convo[idx] = f2bf(acc / (1.f + expf(-acc)));   // SiLU
}

// ---------------- dt = softplus(raw + dt_bias); store {dt, exp(dt*A)} ----------------
__global__ __launch_bounds__(256)
void dt_kernel(const unsigned short* __restrict__ proj, const float* __restrict__ dtb,
               const float* __restrict__ A_log, float2* __restrict__ dts) {
  int idx = blockIdx.x * 256 + threadIdx.x;
  if (idx >= BS * HEADS) return;
  int h  = idx & 63;
  int rs = idx >> 6;
  float x = bf2f(proj[(size_t)rs * PROJ + INTER + CONV_DIM + h]) + dtb[h];
  float dt = (x > 20.f) ? x : log1pf(expf(x));
  float Ah = -expf(A_log[h]);
  dts[idx] = make_float2(dt, expf(dt * Ah));
}

// ---------------- sequential SSM scan (bf16 in/out, f32 state) ----------------
// Block = (b, h, p-half): 256 blocks, 512 threads = 32 p x 16 j.
// Each thread carries 8 states n = j*8+i over the FULL n=128 -> complete y,
// single output buffer. LDS B/C use a +4-per-32-floats swizzle pad so the
// 16-lane x 8-float read is 2-way (free, m136) instead of 4-way.
#define CS 32
#define BCP 140  /* padded row stride for lB/lC: max write = bcswz(124)+4 = 140 (16B-aligned) */
__device__ inline int bcswz(int n) { return n + ((n >> 5) << 2); }

__global__ __launch_bounds__(512)
void scan_kernel(const unsigned short* __restrict__ convo, const float2* __restrict__ dts,
                 unsigned short* __restrict__ yp) {
  __shared__ float lx[CS * 32];
  __shared__ float lB[CS * BCP];
  __shared__ float lC[CS * BCP];
  __shared__ float ly[CS * 32];
  __shared__ float2 ldt[CS];
  const int ph = blockIdx.x & 1;
  const int h  = (blockIdx.x >> 1) & 63;
  const int b  = blockIdx.x >> 7;
  const int t  = threadIdx.x;
  const int j  = t & 15, pl = t >> 4;
  float st[8];
#pragma unroll
  for (int i = 0; i < 8; i++) st[i] = 0.f;
  const size_t row0 = (size_t)b * SEQ;
  const int xcol = h * 64 + ph * 32;

  for (int c0 = 0; c0 < SEQ; c0 += CS) {
    // ---- stage CS rows of x(32), B(128), C(128) as bf16x4 chunks: 72 chunks/row ----
    for (int idx = t; idx < CS * 72; idx += 512) {
      int row = idx / 72;
      int c   = idx - row * 72;
      size_t gro = (row0 + c0 + row) * CONV_DIM;
      if (c < 8) {
        ushort4 v = *(const ushort4*)&convo[gro + xcol + c * 4];
        float* d = &lx[row * 32 + c * 4];
        d[0]=bf2f(v.x); d[1]=bf2f(v.y); d[2]=bf2f(v.z); d[3]=bf2f(v.w);
      } else if (c < 40) {
        int n4 = (c - 8) * 4;
        ushort4 v = *(const ushort4*)&convo[gro + INTER + n4];
        float* d = &lB[row * BCP + bcswz(n4)];
        d[0]=bf2f(v.x); d[1]=bf2f(v.y); d[2]=bf2f(v.z); d[3]=bf2f(v.w);
      } else {
        int n4 = (c - 40) * 4;
        ushort4 v = *(const ushort4*)&convo[gro + INTER + STATE + n4];
        float* d = &lC[row * BCP + bcswz(n4)];
        d[0]=bf2f(v.x); d[1]=bf2f(v.y); d[2]=bf2f(v.z); d[3]=bf2f(v.w);
      }
    }
    if (t < CS) ldt[t] = dts[((row0 + c0 + t) << 6) + h];
    __syncthreads();

    const int nb = bcswz(j * 8);
    for (int sl = 0; sl < CS; ++sl) {
      float2 d = ldt[sl];
      float dtx = d.x * lx[sl * 32 + pl];
      const float4* Bp = (const float4*)&lB[sl * BCP + nb];
      const float4* Cp = (const float4*)&lC[sl * BCP + nb];
      float4 b0 = Bp[0], b1 = Bp[1];
      float4 cv0 = Cp[0], cv1 = Cp[1];
      float yv = 0.f;
      st[0] = st[0]*d.y + dtx*b0.x; yv += st[0]*cv0.x;
      st[1] = st[1]*d.y + dtx*b0.y; yv += st[1]*cv0.y;
      st[2] = st[2]*d.y + dtx*b0.z; yv += st[2]*cv0.z;
      st[3] = st[3]*d.y + dtx*b0.w; yv += st[3]*cv0.w;
      st[4] = st[4]*d.y + dtx*b1.x; yv += st[4]*cv1.x;
      st[5] = st[5]*d.y + dtx*b1.y; yv += st[5]*cv1.y;
      st[6] = st[6]*d.y + dtx*b1.z; yv += st[6]*cv1.z;
      st[7] = st[7]*d.y + dtx*b1.w; yv += st[7]*cv1.w;
      yv += __shfl_xor(yv, 1);
      yv += __shfl_xor(yv, 2);
      yv += __shfl_xor(yv, 4);
      yv += __shfl_xor(yv, 8);
      if (j == 0) ly[sl * 32 + pl] = yv;
    }
    __syncthreads();
    if (t < 256) {
      int row = t >> 3, c = (t & 7) * 4;
      ushort4 o;
      o.x = f2bf(ly[row*32+c+0]); o.y = f2bf(ly[row*32+c+1]);
      o.z = f2bf(ly[row*32+c+2]); o.w = f2bf(ly[row*32+c+3]);
      *(ushort4*)&yp[(row0 + c0 + row) * INTER + xcol + c] = o;
    }
    // next staging writes lx/lB/lC (not ly); next ly write is after the first
    // __syncthreads of the next iteration -> no extra barrier needed here.
  }
}

// ---------------- y = yp + D*x; gated RMSNorm -> bf16 (written into PRJ dead cols) ----------------
__global__ __launch_bounds__(256)
void gated_norm_kernel(const unsigned short* __restrict__ yp,
                       const unsigned short* __restrict__ convo, const unsigned short* __restrict__ proj,
                       const float* __restrict__ Dv, const float* __restrict__ gnw,
                       unsigned short* __restrict__ yn /* = PRJ + YN_COL, stride PROJ */) {
  int row = blockIdx.x;
  int t = threadIdx.x;
  __shared__ float vbuf[INTER];
  __shared__ float red[4];
  __shared__ float scl;
  size_t yo = (size_t)row * INTER;
  size_t co = (size_t)row * CONV_DIM;
  size_t po = (size_t)row * PROJ;
  float ss = 0.f;
  for (int i = t * 4; i < INTER; i += 1024) {
    ushort4 y0 = *(const ushort4*)&yp[yo + i];
    ushort4 xs = *(const ushort4*)&convo[co + i];
    ushort4 g  = *(const ushort4*)&proj[po + i];
    float Dh = Dv[i >> 6];
    float yv[4] = { bf2f(y0.x) + Dh * bf2f(xs.x),
                    bf2f(y0.y) + Dh * bf2f(xs.y),
                    bf2f(y0.z) + Dh * bf2f(xs.z),
                    bf2f(y0.w) + Dh * bf2f(xs.w) };
    float gv[4] = { bf2f(g.x), bf2f(g.y), bf2f(g.z), bf2f(g.w) };
#pragma unroll
    for (int k = 0; k < 4; k++) {
      float v = yv[k] * (gv[k] / (1.f + expf(-gv[k])));
      vbuf[i + k] = v;
      ss += v * v;
    }
  }
  for (int o = 32; o > 0; o >>= 1) ss += __shfl_down(ss, o);
  if ((t & 63) == 0) red[t >> 6] = ss;
  __syncthreads();
  if (t == 0) scl = rsqrtf((red[0]+red[1]+red[2]+red[3]) / (float)INTER + EPS);
  __syncthreads();
  float s = scl;
  for (int i = t * 4; i < INTER; i += 1024) {
    ushort4 o;
    o.x = f2bf(vbuf[i + 0] * s * gnw[i + 0]);
    o.y = f2bf(vbuf[i + 1] * s * gnw[i + 1]);
    o.z = f2bf(vbuf[i + 2] * s * gnw[i + 2]);
    o.w = f2bf(vbuf[i + 3] * s * gnw[i + 3]);
    *(ushort4*)&yn[po + i] = o;   // row stride PROJ, cols YN_COL..YN_COL+4096 (dead conv/dt cols)
  }
}

// ---------------- launch ----------------
extern "C" void kernel_launch(void* const* d_in, const int* in_sizes, int n_in,
                              void* d_out, int out_size, void* d_ws, size_t ws_size,
                              hipStream_t stream) {
  const float* hidden  = (const float*)d_in[0];
  const float* norm_w  = (const float*)d_in[1];
  const float* w1      = (const float*)d_in[2];
  const float* convw   = (const float*)d_in[3];
  const float* convb   = (const float*)d_in[4];
  const float* dt_bias = (const float*)d_in[5];
  const float* A_log   = (const float*)d_in[6];
  const float* Dv      = (const float*)d_in[7];
  const float* gnw     = (const float*)d_in[8];
  const float* w2      = (const float*)d_in[9];
  float* out = (float*)d_out;

  char* ws = (char*)d_ws;
  size_t off = 0;
  auto alloc = [&](size_t bytes) {
    void* p = ws + off;
    off += (bytes + 255) & ~(size_t)255;
    return p;
  };
  // ~176 MB total.
  // Overlays: YP (33.6 MB) reuses XN+W1B (16.8+34.9 MB contiguous, dead after GEMM1).
  //           YN (33.6 MB) lives inside PRJ cols [4160,8256) (conv/dt cols dead after conv).
  unsigned short* XN  = (unsigned short*)alloc((size_t)BS * HID * 2);      // 16.8 MB
  unsigned short* W1B = (unsigned short*)alloc((size_t)PROJ * HID * 2);    // 34.9 MB
  unsigned short* W2B = (unsigned short*)alloc((size_t)HID * INTER * 2);   // 16.8 MB
  unsigned short* PRJ = (unsigned short*)alloc((size_t)BS * PROJ * 2);     // 69.7 MB
  unsigned short* CVO = (unsigned short*)alloc((size_t)BS * CONV_DIM * 2); // 35.7 MB
  float2*         DTS = (float2*)alloc((size_t)BS * HEADS * 8);            //  2.1 MB
  unsigned short* YP  = XN;                    // 33.6 MB <= 51.7 MB (XN+W1B)
  unsigned short* YN  = PRJ + YN_COL;          // in-row overlay, stride PROJ
  if (off > ws_size) return;   // diagnostic: nothing launches -> absmax == 8.6875 exactly
  (void)in_sizes; (void)n_in; (void)out_size;

  int n1 = PROJ * HID / 4;
  cast_bf16_kernel<<<(n1 + 255) / 256, 256, 0, stream>>>((const float4*)w1, (ushort4*)W1B, n1);
  int n2 = HID * INTER / 4;
  cast_bf16_kernel<<<(n2 + 255) / 256, 256, 0, stream>>>((const float4*)w2, (ushort4*)W2B, n2);

  rmsnorm_in_kernel<<<BS, 256, 0, stream>>>(hidden, norm_w, XN);

  gemm_bt_kernel<<<dim3(BS / 128, (PROJ + 127) / 128), 256, 0, stream>>>(
      XN, HID, W1B, nullptr, PRJ, PROJ, BS, PROJ, HID, nullptr);

  conv_silu_kernel<<<(BS * CONV_DIM + 255) / 256, 256, 0, stream>>>(PRJ, convw, convb, CVO);
  dt_kernel<<<(BS * HEADS + 255) / 256, 256, 0, stream>>>(PRJ, dt_bias, A_log, DTS);

  scan_kernel<<<256, 512, 0, stream>>>(CVO, DTS, YP);

  gated_norm_kernel<<<BS, 256, 0, stream>>>(YP, CVO, PRJ, Dv, gnw, YN);

  gemm_bt_kernel<<<dim3(BS / 128, HID / 128), 256, 0, stream>>>(
      YN, PROJ, W2B, out, nullptr, HID, BS, HID, INTER, hidden);
}

// Round 5
// 756.904 us; speedup vs baseline: 1.8743x; 1.8743x over previous
//
#include <hip/hip_runtime.h>
#include <math.h>

#define HID      2048
#define STATE    128
#define HEADS    64
#define HEADDIM  64
#define INTER    4096
#define CONV_DIM 4352
#define PROJ     8512
#define NBATCH   2
#define SEQ      2048
#define BS       (NBATCH*SEQ)   /* 4096 token rows */
#define EPS      1e-5f
#define YN_COL   4160           /* YN lives in PRJ cols [4160, 8256) after conv/dt are dead */

typedef __attribute__((ext_vector_type(8))) short short8;
typedef __attribute__((ext_vector_type(4))) float f32x4;

__device__ inline unsigned short f2bf(float f) {
  union { float f; unsigned int u; } v; v.f = f;
  unsigned int r = v.u + 0x7fffu + ((v.u >> 16) & 1u);   // RNE
  return (unsigned short)(r >> 16);
}
__device__ inline float bf2f(unsigned short b) {
  union { unsigned int u; float f; } v; v.u = ((unsigned int)b) << 16;
  return v.f;
}

// ---------------- f32 -> bf16 cast (weights) ----------------
__global__ __launch_bounds__(256)
void cast_bf16_kernel(const float4* __restrict__ src, ushort4* __restrict__ dst, int n4) {
  int i = blockIdx.x * 256 + threadIdx.x;
  if (i >= n4) return;
  float4 v = src[i];
  ushort4 o;
  o.x = f2bf(v.x); o.y = f2bf(v.y); o.z = f2bf(v.z); o.w = f2bf(v.w);
  dst[i] = o;
}

// ---------------- input RMSNorm -> bf16 ----------------
__global__ __launch_bounds__(256)
void rmsnorm_in_kernel(const float* __restrict__ x, const float* __restrict__ w,
                       unsigned short* __restrict__ xn) {
  int row = blockIdx.x;
  int t = threadIdx.x;
  const float* xr = x + (size_t)row * HID;
  float4 a = ((const float4*)xr)[t];
  float4 b = ((const float4*)xr)[t + 256];
  float ss = a.x*a.x + a.y*a.y + a.z*a.z + a.w*a.w
           + b.x*b.x + b.y*b.y + b.z*b.z + b.w*b.w;
  for (int o = 32; o > 0; o >>= 1) ss += __shfl_down(ss, o);
  __shared__ float red[4];
  __shared__ float scl;
  if ((t & 63) == 0) red[t >> 6] = ss;
  __syncthreads();
  if (t == 0) scl = rsqrtf((red[0]+red[1]+red[2]+red[3]) / (float)HID + EPS);
  __syncthreads();
  float s = scl;
  float4 w0 = ((const float4*)w)[t];
  float4 w1 = ((const float4*)w)[t + 256];
  ushort4 o0, o1;
  o0.x = f2bf(a.x*s*w0.x); o0.y = f2bf(a.y*s*w0.y); o0.z = f2bf(a.z*s*w0.z); o0.w = f2bf(a.w*s*w0.w);
  o1.x = f2bf(b.x*s*w1.x); o1.y = f2bf(b.y*s*w1.y); o1.z = f2bf(b.z*s*w1.z); o1.w = f2bf(b.w*s*w1.w);
  ushort4* dst = (ushort4*)(xn + (size_t)row * HID);
  dst[t] = o0;
  dst[t + 256] = o1;
}

// ---------------- bf16 BT-GEMM: C[M,N] = A[M,K] * B[N,K]^T ----------------
__global__ __launch_bounds__(256)
void gemm_bt_kernel(const unsigned short* __restrict__ A, int lda,
                    const unsigned short* __restrict__ B,
                    float* __restrict__ Cf, unsigned short* __restrict__ Cb, int ldc,
                    int M, int N, int Kd, const float* __restrict__ residual) {
  __shared__ unsigned short As[128 * 32];
  __shared__ unsigned short Bs[128 * 32];
  const int tid  = threadIdx.x;
  const int wave = tid >> 6;
  const int lane = tid & 63;
  const int quad = lane >> 4;
  const int tq   = lane & 15;
  const int m0 = blockIdx.x * 128;
  const int n0 = blockIdx.y * 128;
  const int wm = (wave >> 1) * 64;
  const int wn = (wave & 1) * 64;

  f32x4 acc[4][4];
#pragma unroll
  for (int i = 0; i < 4; i++)
#pragma unroll
    for (int jj = 0; jj < 4; jj++)
      acc[i][jj] = (f32x4){0.f, 0.f, 0.f, 0.f};

  const int ci0 = wave * 128 + lane;
  const int ci1 = ci0 + 64;
  const int rA0 = ci0 >> 2, cA0 = (ci0 & 3) ^ (rA0 & 3);
  const int rA1 = ci1 >> 2, cA1 = (ci1 & 3) ^ (rA1 & 3);
  const unsigned short* gA0 = A + (size_t)(m0 + rA0) * lda + cA0 * 8;
  const unsigned short* gA1 = A + (size_t)(m0 + rA1) * lda + cA1 * 8;
  int nb0 = n0 + rA0; nb0 = (nb0 > N - 1) ? (N - 1) : nb0;
  int nb1 = n0 + rA1; nb1 = (nb1 > N - 1) ? (N - 1) : nb1;
  const unsigned short* gB0 = B + (size_t)nb0 * Kd + cA0 * 8;
  const unsigned short* gB1 = B + (size_t)nb1 * Kd + cA1 * 8;
  unsigned short* lA0 = As + wave * 1024;
  unsigned short* lA1 = As + wave * 1024 + 512;
  unsigned short* lB0 = Bs + wave * 1024;
  unsigned short* lB1 = Bs + wave * 1024 + 512;

  const int kIters = Kd >> 5;
  for (int kt = 0; kt < kIters; ++kt) {
    const int ko = kt << 5;
    __syncthreads();
    __builtin_amdgcn_global_load_lds((const __attribute__((address_space(1))) void*)(gA0 + ko),
                                     (__attribute__((address_space(3))) void*)lA0, 16, 0, 0);
    __builtin_amdgcn_global_load_lds((const __attribute__((address_space(1))) void*)(gA1 + ko),
                                     (__attribute__((address_space(3))) void*)lA1, 16, 0, 0);
    __builtin_amdgcn_global_load_lds((const __attribute__((address_space(1))) void*)(gB0 + ko),
                                     (__attribute__((address_space(3))) void*)lB0, 16, 0, 0);
    __builtin_amdgcn_global_load_lds((const __attribute__((address_space(1))) void*)(gB1 + ko),
                                     (__attribute__((address_space(3))) void*)lB1, 16, 0, 0);
    __syncthreads();

    short8 af[4], bf[4];
#pragma unroll
    for (int mi = 0; mi < 4; mi++) {
      int r = wm + mi * 16 + tq;
      af[mi] = *(const short8*)(As + r * 32 + ((quad ^ (r & 3)) << 3));
    }
#pragma unroll
    for (int ni = 0; ni < 4; ni++) {
      int r = wn + ni * 16 + tq;
      bf[ni] = *(const short8*)(Bs + r * 32 + ((quad ^ (r & 3)) << 3));
    }
#pragma unroll
    for (int mi = 0; mi < 4; mi++)
#pragma unroll
      for (int ni = 0; ni < 4; ni++)
        acc[mi][ni] = __builtin_amdgcn_mfma_f32_16x16x32_bf16(af[mi], bf[ni], acc[mi][ni], 0, 0, 0);
  }

#pragma unroll
  for (int mi = 0; mi < 4; mi++) {
#pragma unroll
    for (int ni = 0; ni < 4; ni++) {
      int col = n0 + wn + ni * 16 + tq;
      if (col < N) {
        int rowb = m0 + wm + mi * 16 + quad * 4;
        if (Cb) {
#pragma unroll
          for (int r = 0; r < 4; r++)
            Cb[(size_t)(rowb + r) * ldc + col] = f2bf(acc[mi][ni][r]);
        } else {
#pragma unroll
          for (int r = 0; r < 4; r++) {
            size_t idx = (size_t)(rowb + r) * N + col;
            float v = acc[mi][ni][r];
            if (residual) v += residual[idx];
            Cf[idx] = v;
          }
        }
      }
    }
  }
}

// ---------------- causal depthwise conv(K=4) + bias + SiLU (bf16 in/out) ----------------
__global__ __launch_bounds__(256)
void conv_silu_kernel(const unsigned short* __restrict__ proj, const float* __restrict__ cw,
                      const float* __restrict__ cb, unsigned short* __restrict__ convo) {
  int idx = blockIdx.x * 256 + threadIdx.x;
  if (idx >= BS * CONV_DIM) return;
  int c  = idx % CONV_DIM;
  int rs = idx / CONV_DIM;
  int s  = rs & (SEQ - 1);
  const unsigned short* col = proj + (size_t)rs * PROJ + INTER + c;
  float acc = cb[c];
#pragma unroll
  for (int k = 0; k < 4; k++) {
    int sp = s - 3 + k;
    if (sp >= 0) acc += bf2f(col[(ptrdiff_t)(k - 3) * PROJ]) * cw[c * 4 + k];
  }
  convo[idx] = f2bf(acc / (1.f + expf(-acc)));   // SiLU
}

// ---------------- dt = softplus(raw + dt_bias); store {dt, dt*A} ----------------
__global__ __launch_bounds__(256)
void dt_kernel(const unsigned short* __restrict__ proj, const float* __restrict__ dtb,
               const float* __restrict__ A_log, float2* __restrict__ dts) {
  int idx = blockIdx.x * 256 + threadIdx.x;
  if (idx >= BS * HEADS) return;
  int h  = idx & 63;
  int rs = idx >> 6;
  float x = bf2f(proj[(size_t)rs * PROJ + INTER + CONV_DIM + h]) + dtb[h];
  float dt = (x > 20.f) ? x : log1pf(expf(x));
  float Ah = -expf(A_log[h]);
  dts[idx] = make_float2(dt, dt * Ah);   // {dt, log-decay increment}
}

// ---------------- SSD chunked scan (MFMA) ----------------
// Block = (b, h, p-half): 256 blocks, 256 threads (4 waves).
// Chunk L=64. Per chunk:
//   G[i,j] = sum_n C[i,n] B[j,n]                      (MFMA, K=128)
//   Ms[i,j] = (j<=i) ? G * exp(cum[i]-cum[j]) * dt[j] : 0
//   Y[i,p] = exp(cum[i]) * sum_n C[i,n] Sb[p,n] + sum_j Ms[i,j] x[j,p]
//   S[p,n] = exp(cum[63]) * S[p,n] + sum_j (exp(cum[63]-cum[j]) dt[j] x[j,p]) B[j,n]
// State S held in fp32 MFMA accumulators; bf16 copy Sb in LDS for the C*S GEMM.
#define LCH 64
#define CST 136   /* row stride (shorts) for Cst/Bst/Sb: 272B = 17x16B aligned */
#define TST 72    /* row stride (shorts) for Btt/xtT/xtw/Msh: 144B aligned */

__global__ __launch_bounds__(256)
void ssd_scan_kernel(const unsigned short* __restrict__ convo, const float2* __restrict__ dts,
                     unsigned short* __restrict__ yp) {
  __shared__ unsigned short Cst[64 * CST];
  __shared__ unsigned short Bst[64 * CST];
  __shared__ unsigned short Btt[128 * TST];   // B transposed [n][j]
  __shared__ unsigned short xtT[32 * TST];    // x transposed [p_local][j]
  __shared__ unsigned short xtw[32 * TST];    // w[j]-weighted x^T
  __shared__ unsigned short Msh[64 * TST];    // masked decay-weighted G [i][j]
  __shared__ unsigned short Sb [32 * CST];    // state bf16 [p_local][n]
  __shared__ float cumL[64], PexL[64], wL[64], dtvL[64], dtaL[64];

  const int ph = blockIdx.x & 1;
  const int h  = (blockIdx.x >> 1) & 63;
  const int b  = blockIdx.x >> 7;
  const int t  = threadIdx.x;
  const int wv = t >> 6;
  const int lane = t & 63;
  const int quad = lane >> 4;
  const int tq   = lane & 15;
  const size_t row0 = (size_t)b * SEQ;
  const int xcol = h * 64 + ph * 32;

  for (int i = t; i < 32 * CST; i += 256) Sb[i] = 0;

  f32x4 s_acc[4];
#pragma unroll
  for (int c = 0; c < 4; c++) s_acc[c] = (f32x4){0.f, 0.f, 0.f, 0.f};
  const int pt  = wv & 1;          // update p-tile: rows 16*pt..
  const int ntb = (wv >> 1) * 4;   // update n-tile base (x16)

  for (int c0 = 0; c0 < SEQ; c0 += LCH) {
    __syncthreads();   // B0: prior chunk's LDS reads done before restaging
    // ---- stage B, C (natural + B transposed), x (transposed), dt ----
#pragma unroll
    for (int it = 0; it < 4; ++it) {
      int id = t + 256 * it;
      int row = id >> 4, cc = id & 15;
      size_t g = (row0 + c0 + row) * CONV_DIM + INTER;
      short8 vb = *(const short8*)&convo[g + cc * 8];
      short8 vc = *(const short8*)&convo[g + STATE + cc * 8];
      *(short8*)&Bst[row * CST + cc * 8] = vb;
      *(short8*)&Cst[row * CST + cc * 8] = vc;
#pragma unroll
      for (int e = 0; e < 8; e++)
        Btt[(cc * 8 + e) * TST + row] = (unsigned short)vb[e];
    }
    {
      int row = t >> 2, cc = t & 3;
      short8 vx = *(const short8*)&convo[(row0 + c0 + row) * CONV_DIM + xcol + cc * 8];
#pragma unroll
      for (int e = 0; e < 8; e++)
        xtT[(cc * 8 + e) * TST + row] = (unsigned short)vx[e];
    }
    if (t < 64) {
      float2 dv = dts[((row0 + c0 + t) << 6) + h];
      dtvL[t] = dv.x; dtaL[t] = dv.y;
    }
    __syncthreads();   // B_s: staging visible

    // ---- cumulative log-decay (each wave redundantly; same values) ----
    {
      float v = dtaL[lane];
#pragma unroll
      for (int off = 1; off < 64; off <<= 1) {
        float u = __shfl_up(v, off);
        if (lane >= off) v += u;
      }
      float tot = __shfl(v, 63);
      cumL[lane] = v;
      PexL[lane] = expf(v);
      wL[lane]   = expf(tot - v) * dtvL[lane];
    }

    // ---- G = C * B^T (wave wv owns i-rows 16wv..16wv+15) ----
    short8 afC[4];
#pragma unroll
    for (int kt = 0; kt < 4; kt++)
      afC[kt] = *(const short8*)&Cst[(16 * wv + tq) * CST + kt * 32 + quad * 8];
    f32x4 g_acc[4];
#pragma unroll
    for (int nj = 0; nj < 4; nj++) g_acc[nj] = (f32x4){0.f, 0.f, 0.f, 0.f};
#pragma unroll
    for (int kt = 0; kt < 4; kt++) {
#pragma unroll
      for (int nj = 0; nj < 4; nj++) {
        short8 bf = *(const short8*)&Bst[(16 * nj + tq) * CST + kt * 32 + quad * 8];
        g_acc[nj] = __builtin_amdgcn_mfma_f32_16x16x32_bf16(afC[kt], bf, g_acc[nj], 0, 0, 0);
      }
    }

    // ---- Ms[i][j] (same-wave write->read; no barrier needed) ----
    {
      float ci[4];
#pragma unroll
      for (int r = 0; r < 4; r++) ci[r] = cumL[16 * wv + quad * 4 + r];
#pragma unroll
      for (int nj = 0; nj < 4; nj++) {
        int j = 16 * nj + tq;
        float cj = cumL[j], dj = dtvL[j];
#pragma unroll
        for (int r = 0; r < 4; r++) {
          int i = 16 * wv + quad * 4 + r;
          float val = (j <= i) ? g_acc[nj][r] * expf(ci[r] - cj) * dj : 0.f;
          Msh[i * TST + j] = f2bf(val);
        }
      }
    }
    // ---- xtw[p][j] = x^T * w[j] (cross-wave reads protected by B1) ----
    {
      int p = t >> 3, c8 = t & 7;
      short8 v = *(const short8*)&xtT[p * TST + c8 * 8];
      short8 o;
#pragma unroll
      for (int e = 0; e < 8; e++)
        o[e] = (short)f2bf(bf2f((unsigned short)v[e]) * wL[c8 * 8 + e]);
      *(short8*)&xtw[p * TST + c8 * 8] = o;
    }

    // ---- Y = Pex[i]*(C*Sb^T) + Ms*x^T ----
    f32x4 yac[2];
    yac[0] = (f32x4){0.f, 0.f, 0.f, 0.f};
    yac[1] = (f32x4){0.f, 0.f, 0.f, 0.f};
#pragma unroll
    for (int kt = 0; kt < 4; kt++) {
#pragma unroll
      for (int np = 0; np < 2; np++) {
        short8 bs = *(const short8*)&Sb[(16 * np + tq) * CST + kt * 32 + quad * 8];
        yac[np] = __builtin_amdgcn_mfma_f32_16x16x32_bf16(afC[kt], bs, yac[np], 0, 0, 0);
      }
    }
    {
      float pex[4];
#pragma unroll
      for (int r = 0; r < 4; r++) pex[r] = PexL[16 * wv + quad * 4 + r];
#pragma unroll
      for (int np = 0; np < 2; np++)
#pragma unroll
        for (int r = 0; r < 4; r++) yac[np][r] *= pex[r];
    }
#pragma unroll
    for (int kt2 = 0; kt2 < 2; kt2++) {
      short8 am = *(const short8*)&Msh[(16 * wv + tq) * TST + kt2 * 32 + quad * 8];
#pragma unroll
      for (int np = 0; np < 2; np++) {
        short8 bx = *(const short8*)&xtT[(16 * np + tq) * TST + kt2 * 32 + quad * 8];
        yac[np] = __builtin_amdgcn_mfma_f32_16x16x32_bf16(am, bx, yac[np], 0, 0, 0);
      }
    }
#pragma unroll
    for (int np = 0; np < 2; np++) {
#pragma unroll
      for (int r = 0; r < 4; r++) {
        int i = 16 * wv + quad * 4 + r;
        int p = ph * 32 + 16 * np + tq;
        yp[(row0 + c0 + i) * INTER + h * 64 + p] = f2bf(yac[np][r]);
      }
    }
    __syncthreads();   // B1: Sb reads (Y_inter) + xtw writes complete

    // ---- state update: S = Ptot*S + xw^T * Bt ----
    {
      float ptot = PexL[63];
#pragma unroll
      for (int c = 0; c < 4; c++)
#pragma unroll
        for (int r = 0; r < 4; r++) s_acc[c][r] *= ptot;
#pragma unroll
      for (int kt2 = 0; kt2 < 2; kt2++) {
        short8 ax = *(const short8*)&xtw[(16 * pt + tq) * TST + kt2 * 32 + quad * 8];
#pragma unroll
        for (int c = 0; c < 4; c++) {
          short8 bb = *(const short8*)&Btt[(16 * (ntb + c) + tq) * TST + kt2 * 32 + quad * 8];
          s_acc[c] = __builtin_amdgcn_mfma_f32_16x16x32_bf16(ax, bb, s_acc[c], 0, 0, 0);
        }
      }
#pragma unroll
      for (int c = 0; c < 4; c++)
#pragma unroll
        for (int r = 0; r < 4; r++) {
          int p = 16 * pt + quad * 4 + r;
          int n = 16 * (ntb + c) + tq;
          Sb[p * CST + n] = f2bf(s_acc[c][r]);
        }
    }
    // next chunk's B0 protects Sb writes before Y_inter reads them
  }
}

// ---------------- y = yp + D*x; gated RMSNorm -> bf16 (into PRJ dead cols) ----------------
__global__ __launch_bounds__(256)
void gated_norm_kernel(const unsigned short* __restrict__ yp,
                       const unsigned short* __restrict__ convo, const unsigned short* __restrict__ proj,
                       const float* __restrict__ Dv, const float* __restrict__ gnw,
                       unsigned short* __restrict__ yn) {
  int row = blockIdx.x;
  int t = threadIdx.x;
  __shared__ float vbuf[INTER];
  __shared__ float red[4];
  __shared__ float scl;
  size_t yo = (size_t)row * INTER;
  size_t co = (size_t)row * CONV_DIM;
  size_t po = (size_t)row * PROJ;
  float ss = 0.f;
  for (int i = t * 4; i < INTER; i += 1024) {
    ushort4 y0 = *(const ushort4*)&yp[yo + i];
    ushort4 xs = *(const ushort4*)&convo[co + i];
    ushort4 g  = *(const ushort4*)&proj[po + i];
    float Dh = Dv[i >> 6];
    float yv[4] = { bf2f(y0.x) + Dh * bf2f(xs.x),
                    bf2f(y0.y) + Dh * bf2f(xs.y),
                    bf2f(y0.z) + Dh * bf2f(xs.z),
                    bf2f(y0.w) + Dh * bf2f(xs.w) };
    float gv[4] = { bf2f(g.x), bf2f(g.y), bf2f(g.z), bf2f(g.w) };
#pragma unroll
    for (int k = 0; k < 4; k++) {
      float v = yv[k] * (gv[k] / (1.f + expf(-gv[k])));
      vbuf[i + k] = v;
      ss += v * v;
    }
  }
  for (int o = 32; o > 0; o >>= 1) ss += __shfl_down(ss, o);
  if ((t & 63) == 0) red[t >> 6] = ss;
  __syncthreads();
  if (t == 0) scl = rsqrtf((red[0]+red[1]+red[2]+red[3]) / (float)INTER + EPS);
  __syncthreads();
  float s = scl;
  for (int i = t * 4; i < INTER; i += 1024) {
    ushort4 o;
    o.x = f2bf(vbuf[i + 0] * s * gnw[i + 0]);
    o.y = f2bf(vbuf[i + 1] * s * gnw[i + 1]);
    o.z = f2bf(vbuf[i + 2] * s * gnw[i + 2]);
    o.w = f2bf(vbuf[i + 3] * s * gnw[i + 3]);
    *(ushort4*)&yn[po + i] = o;
  }
}

// ---------------- launch ----------------
extern "C" void kernel_launch(void* const* d_in, const int* in_sizes, int n_in,
                              void* d_out, int out_size, void* d_ws, size_t ws_size,
                              hipStream_t stream) {
  const float* hidden  = (const float*)d_in[0];
  const float* norm_w  = (const float*)d_in[1];
  const float* w1      = (const float*)d_in[2];
  const float* convw   = (const float*)d_in[3];
  const float* convb   = (const float*)d_in[4];
  const float* dt_bias = (const float*)d_in[5];
  const float* A_log   = (const float*)d_in[6];
  const float* Dv      = (const float*)d_in[7];
  const float* gnw     = (const float*)d_in[8];
  const float* w2      = (const float*)d_in[9];
  float* out = (float*)d_out;

  char* ws = (char*)d_ws;
  size_t off = 0;
  auto alloc = [&](size_t bytes) {
    void* p = ws + off;
    off += (bytes + 255) & ~(size_t)255;
    return p;
  };
  unsigned short* XN  = (unsigned short*)alloc((size_t)BS * HID * 2);      // 16.8 MB
  unsigned short* W1B = (unsigned short*)alloc((size_t)PROJ * HID * 2);    // 34.9 MB
  unsigned short* W2B = (unsigned short*)alloc((size_t)HID * INTER * 2);   // 16.8 MB
  unsigned short* PRJ = (unsigned short*)alloc((size_t)BS * PROJ * 2);     // 69.7 MB
  unsigned short* CVO = (unsigned short*)alloc((size_t)BS * CONV_DIM * 2); // 35.7 MB
  float2*         DTS = (float2*)alloc((size_t)BS * HEADS * 8);            //  2.1 MB
  unsigned short* YP  = XN;                    // overlay: XN+W1B dead after GEMM1
  unsigned short* YN  = PRJ + YN_COL;          // in-row overlay, stride PROJ
  if (off > ws_size) return;
  (void)in_sizes; (void)n_in; (void)out_size;

  int n1 = PROJ * HID / 4;
  cast_bf16_kernel<<<(n1 + 255) / 256, 256, 0, stream>>>((const float4*)w1, (ushort4*)W1B, n1);
  int n2 = HID * INTER / 4;
  cast_bf16_kernel<<<(n2 + 255) / 256, 256, 0, stream>>>((const float4*)w2, (ushort4*)W2B, n2);

  rmsnorm_in_kernel<<<BS, 256, 0, stream>>>(hidden, norm_w, XN);

  gemm_bt_kernel<<<dim3(BS / 128, (PROJ + 127) / 128), 256, 0, stream>>>(
      XN, HID, W1B, nullptr, PRJ, PROJ, BS, PROJ, HID, nullptr);

  conv_silu_kernel<<<(BS * CONV_DIM + 255) / 256, 256, 0, stream>>>(PRJ, convw, convb, CVO);
  dt_kernel<<<(BS * HEADS + 255) / 256, 256, 0, stream>>>(PRJ, dt_bias, A_log, DTS);

  ssd_scan_kernel<<<256, 256, 0, stream>>>(CVO, DTS, YP);

  gated_norm_kernel<<<BS, 256, 0, stream>>>(YP, CVO, PRJ, Dv, gnw, YN);

  gemm_bt_kernel<<<dim3(BS / 128, HID / 128), 256, 0, stream>>>(
      YN, PROJ, W2B, out, nullptr, HID, BS, HID, INTER, hidden);
}

// Round 6
// 745.448 us; speedup vs baseline: 1.9031x; 1.0154x over previous
//
#include <hip/hip_runtime.h>
#include <math.h>

#define HID      2048
#define STATE    128
#define HEADS    64
#define HEADDIM  64
#define INTER    4096
#define CONV_DIM 4352
#define PROJ     8512
#define NBATCH   2
#define SEQ      2048
#define BS       (NBATCH*SEQ)   /* 4096 token rows */
#define EPS      1e-5f
#define YN_COL   4160           /* YN lives in PRJ cols [4160, 8256) after conv/dt are dead */

typedef __attribute__((ext_vector_type(8))) short short8;
typedef __attribute__((ext_vector_type(4))) float f32x4;

__device__ inline unsigned short f2bf(float f) {
  union { float f; unsigned int u; } v; v.f = f;
  unsigned int r = v.u + 0x7fffu + ((v.u >> 16) & 1u);   // RNE
  return (unsigned short)(r >> 16);
}
__device__ inline float bf2f(unsigned short b) {
  union { unsigned int u; float f; } v; v.u = ((unsigned int)b) << 16;
  return v.f;
}

// ---------------- f32 -> bf16 cast (weights) ----------------
__global__ __launch_bounds__(256)
void cast_bf16_kernel(const float4* __restrict__ src, ushort4* __restrict__ dst, int n4) {
  int i = blockIdx.x * 256 + threadIdx.x;
  if (i >= n4) return;
  float4 v = src[i];
  ushort4 o;
  o.x = f2bf(v.x); o.y = f2bf(v.y); o.z = f2bf(v.z); o.w = f2bf(v.w);
  dst[i] = o;
}

// ---------------- input RMSNorm -> bf16 ----------------
__global__ __launch_bounds__(256)
void rmsnorm_in_kernel(const float* __restrict__ x, const float* __restrict__ w,
                       unsigned short* __restrict__ xn) {
  int row = blockIdx.x;
  int t = threadIdx.x;
  const float* xr = x + (size_t)row * HID;
  float4 a = ((const float4*)xr)[t];
  float4 b = ((const float4*)xr)[t + 256];
  float ss = a.x*a.x + a.y*a.y + a.z*a.z + a.w*a.w
           + b.x*b.x + b.y*b.y + b.z*b.z + b.w*b.w;
  for (int o = 32; o > 0; o >>= 1) ss += __shfl_down(ss, o);
  __shared__ float red[4];
  __shared__ float scl;
  if ((t & 63) == 0) red[t >> 6] = ss;
  __syncthreads();
  if (t == 0) scl = rsqrtf((red[0]+red[1]+red[2]+red[3]) / (float)HID + EPS);
  __syncthreads();
  float s = scl;
  float4 w0 = ((const float4*)w)[t];
  float4 w1 = ((const float4*)w)[t + 256];
  ushort4 o0, o1;
  o0.x = f2bf(a.x*s*w0.x); o0.y = f2bf(a.y*s*w0.y); o0.z = f2bf(a.z*s*w0.z); o0.w = f2bf(a.w*s*w0.w);
  o1.x = f2bf(b.x*s*w1.x); o1.y = f2bf(b.y*s*w1.y); o1.z = f2bf(b.z*s*w1.z); o1.w = f2bf(b.w*s*w1.w);
  ushort4* dst = (ushort4*)(xn + (size_t)row * HID);
  dst[t] = o0;
  dst[t + 256] = o1;
}

// ---------------- bf16 BT-GEMM: C[M,N] = A[M,K] * B[N,K]^T ----------------
__global__ __launch_bounds__(256)
void gemm_bt_kernel(const unsigned short* __restrict__ A, int lda,
                    const unsigned short* __restrict__ B,
                    float* __restrict__ Cf, unsigned short* __restrict__ Cb, int ldc,
                    int M, int N, int Kd, const float* __restrict__ residual) {
  __shared__ unsigned short As[128 * 32];
  __shared__ unsigned short Bs[128 * 32];
  const int tid  = threadIdx.x;
  const int wave = tid >> 6;
  const int lane = tid & 63;
  const int quad = lane >> 4;
  const int tq   = lane & 15;
  const int m0 = blockIdx.x * 128;
  const int n0 = blockIdx.y * 128;
  const int wm = (wave >> 1) * 64;
  const int wn = (wave & 1) * 64;

  f32x4 acc[4][4];
#pragma unroll
  for (int i = 0; i < 4; i++)
#pragma unroll
    for (int jj = 0; jj < 4; jj++)
      acc[i][jj] = (f32x4){0.f, 0.f, 0.f, 0.f};

  const int ci0 = wave * 128 + lane;
  const int ci1 = ci0 + 64;
  const int rA0 = ci0 >> 2, cA0 = (ci0 & 3) ^ (rA0 & 3);
  const int rA1 = ci1 >> 2, cA1 = (ci1 & 3) ^ (rA1 & 3);
  const unsigned short* gA0 = A + (size_t)(m0 + rA0) * lda + cA0 * 8;
  const unsigned short* gA1 = A + (size_t)(m0 + rA1) * lda + cA1 * 8;
  int nb0 = n0 + rA0; nb0 = (nb0 > N - 1) ? (N - 1) : nb0;
  int nb1 = n0 + rA1; nb1 = (nb1 > N - 1) ? (N - 1) : nb1;
  const unsigned short* gB0 = B + (size_t)nb0 * Kd + cA0 * 8;
  const unsigned short* gB1 = B + (size_t)nb1 * Kd + cA1 * 8;
  unsigned short* lA0 = As + wave * 1024;
  unsigned short* lA1 = As + wave * 1024 + 512;
  unsigned short* lB0 = Bs + wave * 1024;
  unsigned short* lB1 = Bs + wave * 1024 + 512;

  const int kIters = Kd >> 5;
  for (int kt = 0; kt < kIters; ++kt) {
    const int ko = kt << 5;
    __syncthreads();
    __builtin_amdgcn_global_load_lds((const __attribute__((address_space(1))) void*)(gA0 + ko),
                                     (__attribute__((address_space(3))) void*)lA0, 16, 0, 0);
    __builtin_amdgcn_global_load_lds((const __attribute__((address_space(1))) void*)(gA1 + ko),
                                     (__attribute__((address_space(3))) void*)lA1, 16, 0, 0);
    __builtin_amdgcn_global_load_lds((const __attribute__((address_space(1))) void*)(gB0 + ko),
                                     (__attribute__((address_space(3))) void*)lB0, 16, 0, 0);
    __builtin_amdgcn_global_load_lds((const __attribute__((address_space(1))) void*)(gB1 + ko),
                                     (__attribute__((address_space(3))) void*)lB1, 16, 0, 0);
    __syncthreads();

    short8 af[4], bf[4];
#pragma unroll
    for (int mi = 0; mi < 4; mi++) {
      int r = wm + mi * 16 + tq;
      af[mi] = *(const short8*)(As + r * 32 + ((quad ^ (r & 3)) << 3));
    }
#pragma unroll
    for (int ni = 0; ni < 4; ni++) {
      int r = wn + ni * 16 + tq;
      bf[ni] = *(const short8*)(Bs + r * 32 + ((quad ^ (r & 3)) << 3));
    }
#pragma unroll
    for (int mi = 0; mi < 4; mi++)
#pragma unroll
      for (int ni = 0; ni < 4; ni++)
        acc[mi][ni] = __builtin_amdgcn_mfma_f32_16x16x32_bf16(af[mi], bf[ni], acc[mi][ni], 0, 0, 0);
  }

#pragma unroll
  for (int mi = 0; mi < 4; mi++) {
#pragma unroll
    for (int ni = 0; ni < 4; ni++) {
      int col = n0 + wn + ni * 16 + tq;
      if (col < N) {
        int rowb = m0 + wm + mi * 16 + quad * 4;
        if (Cb) {
#pragma unroll
          for (int r = 0; r < 4; r++)
            Cb[(size_t)(rowb + r) * ldc + col] = f2bf(acc[mi][ni][r]);
        } else {
#pragma unroll
          for (int r = 0; r < 4; r++) {
            size_t idx = (size_t)(rowb + r) * N + col;
            float v = acc[mi][ni][r];
            if (residual) v += residual[idx];
            Cf[idx] = v;
          }
        }
      }
    }
  }
}

// ---------------- fused causal conv(K=4)+SiLU and dt=softplus ----------------
__global__ __launch_bounds__(256)
void conv_dt_kernel(const unsigned short* __restrict__ proj, const float* __restrict__ cw,
                    const float* __restrict__ cb, const float* __restrict__ dtb,
                    const float* __restrict__ A_log,
                    unsigned short* __restrict__ convo, float2* __restrict__ dts) {
  int idx = blockIdx.x * 256 + threadIdx.x;
  if (idx < BS * CONV_DIM) {
    int c  = idx % CONV_DIM;
    int rs = idx / CONV_DIM;
    int s  = rs & (SEQ - 1);
    const unsigned short* col = proj + (size_t)rs * PROJ + INTER + c;
    float acc = cb[c];
#pragma unroll
    for (int k = 0; k < 4; k++) {
      int sp = s - 3 + k;
      if (sp >= 0) acc += bf2f(col[(ptrdiff_t)(k - 3) * PROJ]) * cw[c * 4 + k];
    }
    convo[idx] = f2bf(acc / (1.f + expf(-acc)));   // SiLU
  } else {
    int k = idx - BS * CONV_DIM;
    if (k < BS * HEADS) {
      int h  = k & 63;
      int rs = k >> 6;
      float x = bf2f(proj[(size_t)rs * PROJ + INTER + CONV_DIM + h]) + dtb[h];
      float dt = (x > 20.f) ? x : log1pf(expf(x));
      float Ah = -expf(A_log[h]);
      dts[k] = make_float2(dt, dt * Ah);   // {dt, log-decay increment}
    }
  }
}

// ---------------- SSD chunked scan (MFMA), 8 waves: Y-path || S-path ----------------
// Block = (b, h, p-half): 256 blocks, 512 threads.
// Waves 0-3 (Y): G=C*B^T -> Ms (masked decay) -> Y = Pex*(C*Sb^T) + Ms*x^T
// Waves 4-7 (S): ax = (x^T weighted by exp(tot-cum)*dt) in regs -> S = Ptot*S + ax*Btt
// Sb double-buffered; cumsum distributed per-wave via shuffles (no extra barrier).
// 2 barriers per chunk.
#define LCH 64
#define CST 136   /* row stride (shorts) for Cst/Bst/Sb */
#define TST 72    /* row stride (shorts) for Btt/xtT/Msh */

__global__ __launch_bounds__(512)
void ssd_scan_kernel(const unsigned short* __restrict__ convo, const float2* __restrict__ dts,
                     unsigned short* __restrict__ yp) {
  __shared__ unsigned short Cst[64 * CST];
  __shared__ unsigned short Bst[64 * CST];
  __shared__ unsigned short Btt[128 * TST];   // B transposed [n][j]
  __shared__ unsigned short xtT[32 * TST];    // x transposed [p_local][j]
  __shared__ unsigned short Msh[64 * TST];    // masked decay-weighted G [i][j]
  __shared__ unsigned short Sb[2][32 * CST];  // state bf16 [p_local][n], double-buffered
  __shared__ float dtaL[64], dtvL[64];

  const int ph = blockIdx.x & 1;
  const int h  = (blockIdx.x >> 1) & 63;
  const int b  = blockIdx.x >> 7;
  const int t  = threadIdx.x;
  const int wv = t >> 6;
  const int lane = t & 63;
  const int quad = lane >> 4;
  const int tq   = lane & 15;
  const size_t row0 = (size_t)b * SEQ;
  const int xcol = h * 64 + ph * 32;

  for (int i = t; i < 32 * CST; i += 512) Sb[0][i] = 0;

  // S-wave (wv>=4) persistent state accumulators
  f32x4 s_acc[4];
#pragma unroll
  for (int c = 0; c < 4; c++) s_acc[c] = (f32x4){0.f, 0.f, 0.f, 0.f};
  const int pt  = wv & 1;               // S-wave p-tile (0/1)
  const int ntb = ((wv >> 1) & 1) * 4;  // S-wave n-tile base (x16)

  int pp = 0;
  for (int c0 = 0; c0 < SEQ; c0 += LCH, pp ^= 1) {
    __syncthreads();   // B0: prior chunk's compute reads done before restaging
    // ---- stage B, C (natural), B^T, x^T, dt ----
#pragma unroll
    for (int it = 0; it < 2; ++it) {
      int id = t + 512 * it;           // [0,1024): row 0..63, cc 0..15
      int row = id >> 4, cc = id & 15;
      size_t g = (row0 + c0 + row) * CONV_DIM + INTER;
      short8 vb = *(const short8*)&convo[g + cc * 8];
      short8 vc = *(const short8*)&convo[g + STATE + cc * 8];
      *(short8*)&Bst[row * CST + cc * 8] = vb;
      *(short8*)&Cst[row * CST + cc * 8] = vc;
#pragma unroll
      for (int e = 0; e < 8; e++)
        Btt[(cc * 8 + e) * TST + row] = (unsigned short)vb[e];
    }
    {
      int row = t >> 3, c = t & 7;     // 64 rows x 8 chunks of 4
      ushort4 vx = *(const ushort4*)&convo[(row0 + c0 + row) * CONV_DIM + xcol + c * 4];
      xtT[(c * 4 + 0) * TST + row] = vx.x;
      xtT[(c * 4 + 1) * TST + row] = vx.y;
      xtT[(c * 4 + 2) * TST + row] = vx.z;
      xtT[(c * 4 + 3) * TST + row] = vx.w;
    }
    if (t < 64) {
      float2 dv = dts[((row0 + c0 + t) << 6) + h];
      dtvL[t] = dv.x; dtaL[t] = dv.y;
    }
    __syncthreads();   // S1: staging visible

    // ---- per-wave cumulative log-decay scan (lane l holds cum[l]) ----
    float v = dtaL[lane];
#pragma unroll
    for (int off = 1; off < 64; off <<= 1) {
      float u = __shfl_up(v, off);
      if (lane >= off) v += u;
    }
    float tot = __shfl(v, 63);

    if (wv < 4) {
      // ================= Y-path =================
      short8 afC[4];
#pragma unroll
      for (int kt = 0; kt < 4; kt++)
        afC[kt] = *(const short8*)&Cst[(16 * wv + tq) * CST + kt * 32 + quad * 8];
      f32x4 g_acc[4];
#pragma unroll
      for (int nj = 0; nj < 4; nj++) g_acc[nj] = (f32x4){0.f, 0.f, 0.f, 0.f};
#pragma unroll
      for (int kt = 0; kt < 4; kt++) {
#pragma unroll
        for (int nj = 0; nj < 4; nj++) {
          short8 bfr = *(const short8*)&Bst[(16 * nj + tq) * CST + kt * 32 + quad * 8];
          g_acc[nj] = __builtin_amdgcn_mfma_f32_16x16x32_bf16(afC[kt], bfr, g_acc[nj], 0, 0, 0);
        }
      }
      float ci[4], pex[4];
#pragma unroll
      for (int r = 0; r < 4; r++) {
        ci[r] = __shfl(v, 16 * wv + quad * 4 + r);
        pex[r] = expf(ci[r]);
      }
#pragma unroll
      for (int nj = 0; nj < 4; nj++) {
        int j = 16 * nj + tq;
        float cj = __shfl(v, j);
        float dj = dtvL[j];
#pragma unroll
        for (int r = 0; r < 4; r++) {
          int i = 16 * wv + quad * 4 + r;
          float val = (j <= i) ? g_acc[nj][r] * expf(ci[r] - cj) * dj : 0.f;
          Msh[i * TST + j] = f2bf(val);
        }
      }
      // Y = Pex*(C*Sb^T) + Ms*x^T
      f32x4 yac[2];
      yac[0] = (f32x4){0.f, 0.f, 0.f, 0.f};
      yac[1] = (f32x4){0.f, 0.f, 0.f, 0.f};
#pragma unroll
      for (int kt = 0; kt < 4; kt++) {
#pragma unroll
        for (int np = 0; np < 2; np++) {
          short8 bs = *(const short8*)&Sb[pp][(16 * np + tq) * CST + kt * 32 + quad * 8];
          yac[np] = __builtin_amdgcn_mfma_f32_16x16x32_bf16(afC[kt], bs, yac[np], 0, 0, 0);
        }
      }
#pragma unroll
      for (int np = 0; np < 2; np++)
#pragma unroll
        for (int r = 0; r < 4; r++) yac[np][r] *= pex[r];
#pragma unroll
      for (int kt2 = 0; kt2 < 2; kt2++) {
        short8 am = *(const short8*)&Msh[(16 * wv + tq) * TST + kt2 * 32 + quad * 8];
#pragma unroll
        for (int np = 0; np < 2; np++) {
          short8 bx = *(const short8*)&xtT[(16 * np + tq) * TST + kt2 * 32 + quad * 8];
          yac[np] = __builtin_amdgcn_mfma_f32_16x16x32_bf16(am, bx, yac[np], 0, 0, 0);
        }
      }
#pragma unroll
      for (int np = 0; np < 2; np++) {
#pragma unroll
        for (int r = 0; r < 4; r++) {
          int i = 16 * wv + quad * 4 + r;
          int p = ph * 32 + 16 * np + tq;
          yp[(row0 + c0 + i) * INTER + h * 64 + p] = f2bf(yac[np][r]);
        }
      }
    } else {
      // ================= S-path =================
      float ptot = expf(tot);
      short8 ax[2];
#pragma unroll
      for (int kt2 = 0; kt2 < 2; kt2++) {
        short8 xv = *(const short8*)&xtT[(16 * pt + tq) * TST + kt2 * 32 + quad * 8];
#pragma unroll
        for (int e = 0; e < 8; e++) {
          int j = kt2 * 32 + quad * 8 + e;
          float cj = __shfl(v, j);
          float wj = expf(tot - cj) * dtvL[j];
          ax[kt2][e] = (short)f2bf(bf2f((unsigned short)xv[e]) * wj);
        }
      }
#pragma unroll
      for (int c = 0; c < 4; c++)
#pragma unroll
        for (int r = 0; r < 4; r++) s_acc[c][r] *= ptot;
#pragma unroll
      for (int kt2 = 0; kt2 < 2; kt2++) {
#pragma unroll
        for (int c = 0; c < 4; c++) {
          short8 bb = *(const short8*)&Btt[(16 * (ntb + c) + tq) * TST + kt2 * 32 + quad * 8];
          s_acc[c] = __builtin_amdgcn_mfma_f32_16x16x32_bf16(ax[kt2], bb, s_acc[c], 0, 0, 0);
        }
      }
#pragma unroll
      for (int c = 0; c < 4; c++)
#pragma unroll
        for (int r = 0; r < 4; r++) {
          int p = 16 * pt + quad * 4 + r;
          int n = 16 * (ntb + c) + tq;
          Sb[pp ^ 1][p * CST + n] = f2bf(s_acc[c][r]);
        }
    }
    // next chunk's B0 protects Sb[pp^1] writes before Y reads them
  }
}

// ---------------- y = yp + D*x; gated RMSNorm -> bf16 (registers, no LDS buf) ----------------
__global__ __launch_bounds__(256)
void gated_norm_kernel(const unsigned short* __restrict__ yp,
                       const unsigned short* __restrict__ convo, const unsigned short* __restrict__ proj,
                       const float* __restrict__ Dv, const float* __restrict__ gnw,
                       unsigned short* __restrict__ yn) {
  int row = blockIdx.x;
  int t = threadIdx.x;
  __shared__ float red[4];
  __shared__ float scl;
  size_t yo = (size_t)row * INTER;
  size_t co = (size_t)row * CONV_DIM;
  size_t po = (size_t)row * PROJ;
  float vv[16];
  float ss = 0.f;
#pragma unroll
  for (int c = 0; c < 4; c++) {
    int i = t * 4 + c * 1024;
    ushort4 y0 = *(const ushort4*)&yp[yo + i];
    ushort4 xs = *(const ushort4*)&convo[co + i];
    ushort4 g  = *(const ushort4*)&proj[po + i];
    float Dh = Dv[i >> 6];
    float yv[4] = { bf2f(y0.x) + Dh * bf2f(xs.x),
                    bf2f(y0.y) + Dh * bf2f(xs.y),
                    bf2f(y0.z) + Dh * bf2f(xs.z),
                    bf2f(y0.w) + Dh * bf2f(xs.w) };
    float gv[4] = { bf2f(g.x), bf2f(g.y), bf2f(g.z), bf2f(g.w) };
#pragma unroll
    for (int k = 0; k < 4; k++) {
      float val = yv[k] * (gv[k] / (1.f + expf(-gv[k])));
      vv[c * 4 + k] = val;
      ss += val * val;
    }
  }
  for (int o = 32; o > 0; o >>= 1) ss += __shfl_down(ss, o);
  if ((t & 63) == 0) red[t >> 6] = ss;
  __syncthreads();
  if (t == 0) scl = rsqrtf((red[0]+red[1]+red[2]+red[3]) / (float)INTER + EPS);
  __syncthreads();
  float s = scl;
#pragma unroll
  for (int c = 0; c < 4; c++) {
    int i = t * 4 + c * 1024;
    ushort4 o;
    o.x = f2bf(vv[c*4+0] * s * gnw[i + 0]);
    o.y = f2bf(vv[c*4+1] * s * gnw[i + 1]);
    o.z = f2bf(vv[c*4+2] * s * gnw[i + 2]);
    o.w = f2bf(vv[c*4+3] * s * gnw[i + 3]);
    *(ushort4*)&yn[po + i] = o;
  }
}

// ---------------- launch ----------------
extern "C" void kernel_launch(void* const* d_in, const int* in_sizes, int n_in,
                              void* d_out, int out_size, void* d_ws, size_t ws_size,
                              hipStream_t stream) {
  const float* hidden  = (const float*)d_in[0];
  const float* norm_w  = (const float*)d_in[1];
  const float* w1      = (const float*)d_in[2];
  const float* convw   = (const float*)d_in[3];
  const float* convb   = (const float*)d_in[4];
  const float* dt_bias = (const float*)d_in[5];
  const float* A_log   = (const float*)d_in[6];
  const float* Dv      = (const float*)d_in[7];
  const float* gnw     = (const float*)d_in[8];
  const float* w2      = (const float*)d_in[9];
  float* out = (float*)d_out;

  char* ws = (char*)d_ws;
  size_t off = 0;
  auto alloc = [&](size_t bytes) {
    void* p = ws + off;
    off += (bytes + 255) & ~(size_t)255;
    return p;
  };
  unsigned short* XN  = (unsigned short*)alloc((size_t)BS * HID * 2);      // 16.8 MB
  unsigned short* W1B = (unsigned short*)alloc((size_t)PROJ * HID * 2);    // 34.9 MB
  unsigned short* W2B = (unsigned short*)alloc((size_t)HID * INTER * 2);   // 16.8 MB
  unsigned short* PRJ = (unsigned short*)alloc((size_t)BS * PROJ * 2);     // 69.7 MB
  unsigned short* CVO = (unsigned short*)alloc((size_t)BS * CONV_DIM * 2); // 35.7 MB
  float2*         DTS = (float2*)alloc((size_t)BS * HEADS * 8);            //  2.1 MB
  unsigned short* YP  = XN;                    // overlay: XN+W1B dead after GEMM1
  unsigned short* YN  = PRJ + YN_COL;          // in-row overlay, stride PROJ
  if (off > ws_size) return;
  (void)in_sizes; (void)n_in; (void)out_size;

  int n1 = PROJ * HID / 4;
  cast_bf16_kernel<<<(n1 + 255) / 256, 256, 0, stream>>>((const float4*)w1, (ushort4*)W1B, n1);
  int n2 = HID * INTER / 4;
  cast_bf16_kernel<<<(n2 + 255) / 256, 256, 0, stream>>>((const float4*)w2, (ushort4*)W2B, n2);

  rmsnorm_in_kernel<<<BS, 256, 0, stream>>>(hidden, norm_w, XN);

  gemm_bt_kernel<<<dim3(BS / 128, (PROJ + 127) / 128), 256, 0, stream>>>(
      XN, HID, W1B, nullptr, PRJ, PROJ, BS, PROJ, HID, nullptr);

  conv_dt_kernel<<<(BS * (CONV_DIM + HEADS) + 255) / 256, 256, 0, stream>>>(
      PRJ, convw, convb, dt_bias, A_log, CVO, DTS);

  ssd_scan_kernel<<<256, 512, 0, stream>>>(CVO, DTS, YP);

  gated_norm_kernel<<<BS, 256, 0, stream>>>(YP, CVO, PRJ, Dv, gnw, YN);

  gemm_bt_kernel<<<dim3(BS / 128, HID / 128), 256, 0, stream>>>(
      YN, PROJ, W2B, out, nullptr, HID, BS, HID, INTER, hidden);
}